// Round 1
// baseline (503.328 us; speedup 1.0000x reference)
//
#include <hip/hip_runtime.h>
#include <math.h>

#define TT 128      // tags
#define SS 512      // seq len
#define NB 256      // batch
#define START_TAG 126
#define STOP_TAG 127
#define NEGV -10000.0f

__device__ __forceinline__ float wave_max(float v) {
#pragma unroll
    for (int off = 32; off >= 1; off >>= 1)
        v = fmaxf(v, __shfl_xor(v, off));
    return v;
}
__device__ __forceinline__ float wave_sum(float v) {
#pragma unroll
    for (int off = 32; off >= 1; off >>= 1)
        v += __shfl_xor(v, off);
    return v;
}

// One block per batch element. 256 threads = 4 waves.
// Threads t<128 ("consumers", waves 0-1): own tag=t, k-range [0,64)
// Threads t>=128 ("partners", waves 2-3): own tag=t-128, k-range [64,128)
// E[tag][k-half] lives in 64 VGPRs per thread. p (normalized exp(fv)) in LDS,
// read as wave-uniform float4 broadcasts.
__global__ __launch_bounds__(256) void crf_fwd_kernel(
    const float* __restrict__ feats,
    const float* __restrict__ trans,
    const int*   __restrict__ targets,
    float*       __restrict__ out)
{
    const int t    = threadIdx.x;
    const int b    = blockIdx.x;
    const int tag  = t & (TT - 1);
    const int half = t >> 7;

    __shared__ __align__(16) float p_lds[TT];
    __shared__ float stash[TT];
    __shared__ float wm[2][2];   // per-wave max normalizers, parity double-buffered
    __shared__ float redz[8];

    // ---- load E fragment: E[tag][half*64 + j] = exp(trans[tag][half*64+j]) ----
    float E[64];
    {
        const float* trow = trans + tag * TT + half * 64;
#pragma unroll
        for (int j = 0; j < 64; j += 4) {
            float4 tv = *reinterpret_cast<const float4*>(trow + j);
            E[j + 0] = __expf(tv.x);
            E[j + 1] = __expf(tv.y);
            E[j + 2] = __expf(tv.z);
            E[j + 3] = __expf(tv.w);
        }
    }

    const size_t bst = (size_t)b * (SS * TT);
    const float* fb = feats + bst + tag;   // consumer feats column (t<128: tag==t)

    float fv = 0.0f, fcur = 0.0f, f1 = 0.0f, f2 = 0.0f;
    if (t < TT) {
        fv = (t == START_TAG) ? 0.0f : NEGV;
        float mh = wave_max(fv);             // per-wave normalizer
        if ((t & 63) == 0) wm[0][t >> 6] = mh;
        p_lds[t] = __expf(fv - mh);
        // prefetch pipeline, depth 3
        fcur = fb[0 * TT];
        f1   = fb[1 * TT];
        f2   = fb[2 * TT];
    }
    __syncthreads();

    for (int s = 0; s < SS; ++s) {
        // issue feats prefetch for s+3 early (consumers only)
        float fnew = 0.0f;
        if (t < TT) {
            int sn = s + 3; sn = (sn < SS) ? sn : (SS - 1);
            fnew = fb[sn * TT];
        }

        // ---- dot over this thread's k-half (p broadcast from LDS) ----
        float a0 = 0.f, a1 = 0.f, a2 = 0.f, a3 = 0.f;
        const float* pp = p_lds + half * 64;
#pragma unroll
        for (int j = 0; j < 16; ++j) {
            float4 pv = *reinterpret_cast<const float4*>(pp + 4 * j);
            a0 = fmaf(pv.x, E[4 * j + 0], a0);
            a1 = fmaf(pv.y, E[4 * j + 1], a1);
            a2 = fmaf(pv.z, E[4 * j + 2], a2);
            a3 = fmaf(pv.w, E[4 * j + 3], a3);
        }
        float acc = (a0 + a1) + (a2 + a3);
        if (t >= TT) stash[tag] = acc;
        __syncthreads();   // B1: stash + (prev iter's) p fully consumed

        if (t < TT) {
            // combine halves with per-wave normalizer correction
            float M0 = wm[s & 1][0], M1 = wm[s & 1][1];
            float M  = fmaxf(M0, M1);
            float tot = acc * __expf(M0 - M) + stash[tag] * __expf(M1 - M);
            fv = __logf(tot) + M + fcur;

            // new per-wave normalizer + p for next step
            float mh = wave_max(fv);
            if ((t & 63) == 0) wm[(s + 1) & 1][t >> 6] = mh;
            p_lds[t] = __expf(fv - mh);

            // rotate feats prefetch pipeline
            fcur = f1; f1 = f2; f2 = fnew;
        }
        __syncthreads();   // B2: new p visible before next dot
    }

    // ---- gold path score (all 256 threads gather) ----
    const int* tg = targets + b * SS;
    float g = 0.0f;
#pragma unroll
    for (int s = t; s < SS; s += 256) {
        int cur  = tg[s];
        int prev = (s == 0) ? START_TAG : tg[s - 1];
        g += trans[cur * TT + prev] + feats[bst + (size_t)s * TT + cur];
    }
    if (t == 0) g += trans[STOP_TAG * TT + tg[SS - 1]];
    g = wave_sum(g);
    if ((t & 63) == 0) redz[t >> 6] = g;

    // ---- alpha = LSE(fv + trans[STOP, :]) ----
    float vstop = 0.0f;
    if (t < TT) {
        vstop = fv + trans[STOP_TAG * TT + t];
        float mh = wave_max(vstop);
        if ((t & 63) == 0) redz[4 + (t >> 6)] = mh;
    }
    __syncthreads();

    if (t < TT) {
        float M = fmaxf(redz[4], redz[5]);
        float e = __expf(vstop - M);
        float sm = wave_sum(e);
        if ((t & 63) == 0) stash[t >> 6] = sm;   // stash free now
    }
    __syncthreads();

    if (t == 0) {
        float gold  = (redz[0] + redz[1]) + (redz[2] + redz[3]);
        float M     = fmaxf(redz[4], redz[5]);
        float alpha = M + __logf(stash[0] + stash[1]);
        out[b] = gold - alpha;
    }
}

extern "C" void kernel_launch(void* const* d_in, const int* in_sizes, int n_in,
                              void* d_out, int out_size, void* d_ws, size_t ws_size,
                              hipStream_t stream) {
    const float* feats   = (const float*)d_in[0];
    const float* trans   = (const float*)d_in[1];
    const int*   targets = (const int*)d_in[2];
    float*       out     = (float*)d_out;
    crf_fwd_kernel<<<dim3(NB), dim3(256), 0, stream>>>(feats, trans, targets, out);
}

// Round 2
// 406.247 us; speedup vs baseline: 1.2390x; 1.2390x over previous
//
#include <hip/hip_runtime.h>
#include <math.h>

#define TT 128
#define SS 512
#define NB 256
#define START_TAG 126
#define STOP_TAG 127

__device__ __forceinline__ float rlane(float v, int lane) {
    return __int_as_float(__builtin_amdgcn_readlane(__float_as_int(v), lane));
}
__device__ __forceinline__ float wave_max(float v) {
#pragma unroll
    for (int off = 32; off >= 1; off >>= 1) v = fmaxf(v, __shfl_xor(v, off));
    return v;
}
__device__ __forceinline__ float wave_sum(float v) {
#pragma unroll
    for (int off = 32; off >= 1; off >>= 1) v += __shfl_xor(v, off);
    return v;
}

// One block per batch. 4 waves; wave w owns k-quarter [32w, 32w+32).
// Lane l owns tag pair (l, l+64): E2[j] = (exp(trans[l][32w+j]), exp(trans[l+64][32w+j])).
// Full p-vector lives in every wave's registers as pairs (px, py), recomputed
// redundantly each step -> dot needs only v_readlane, no LDS. Only the k-quarter
// partials cross waves: 1 float2 write + 3 reads + ONE barrier per step
// (parity double-buffered). Normalizer = absolute fv[tag 0] via readlane.
__global__ __launch_bounds__(256) void crf_fwd_kernel(
    const float* __restrict__ feats,
    const float* __restrict__ trans,
    const int*   __restrict__ targets,
    float*       __restrict__ out)
{
    const int t = threadIdx.x;
    const int b = blockIdx.x;
    const int w = t >> 6;
    const int l = t & 63;

    __shared__ float2 part[2][4][64];   // [parity][wave][lane]
    __shared__ float redz[4];
    __shared__ float galpha;

    // ---- E fragment in VGPRs ----
    float2 E2[32];
    {
        const float* r0 = trans + l * TT + w * 32;
        const float* r1 = trans + (l + 64) * TT + w * 32;
#pragma unroll
        for (int j = 0; j < 32; j += 4) {
            float4 a0 = *reinterpret_cast<const float4*>(r0 + j);
            float4 a1 = *reinterpret_cast<const float4*>(r1 + j);
            E2[j + 0] = make_float2(__expf(a0.x), __expf(a1.x));
            E2[j + 1] = make_float2(__expf(a0.y), __expf(a1.y));
            E2[j + 2] = make_float2(__expf(a0.z), __expf(a1.z));
            E2[j + 3] = make_float2(__expf(a0.w), __expf(a1.w));
        }
    }

    const size_t bst = (size_t)b * (SS * TT);
    const float* fb = feats + bst + l;

    // feats prefetch pipeline, depth 4 (each wave loads redundantly; L1 absorbs)
    float f0x = fb[0 * TT], f0y = fb[0 * TT + 64];
    float f1x = fb[1 * TT], f1y = fb[1 * TT + 64];
    float f2x = fb[2 * TT], f2y = fb[2 * TT + 64];
    float f3x = fb[3 * TT], f3y = fb[3 * TT + 64];

    // init: p one-hot at START=126 (y-half, lane 62); normalizer M = 0 (absolute)
    float px = 0.f;
    float py = (l == 62) ? 1.f : 0.f;
    float psel = (w >= 2) ? py : px;
    float M = 0.f;
    float fvx = 0.f, fvy = 0.f;
    const int base = (w & 1) << 5;

    for (int s = 0; s < SS; ++s) {
        // issue feats prefetch for s+4
        int sn = s + 4; sn = (sn < SS) ? sn : (SS - 1);
        float fnx = fb[(size_t)sn * TT];
        float fny = fb[(size_t)sn * TT + 64];

        // ---- dot over this wave's k-quarter, pure registers ----
        float ax = 0.f, ay = 0.f;
#pragma unroll
        for (int j = 0; j < 32; ++j) {
            float pj = rlane(psel, base + j);
            ax = fmaf(pj, E2[j].x, ax);
            ay = fmaf(pj, E2[j].y, ay);
        }
        part[s & 1][w][l] = make_float2(ax, ay);
        __syncthreads();

        // ---- redundant combine in every wave (no second barrier) ----
        float2 b1 = part[s & 1][w ^ 1][l];
        float2 b2 = part[s & 1][w ^ 2][l];
        float2 b3 = part[s & 1][w ^ 3][l];
        float tx = (ax + b1.x) + (b2.x + b3.x);
        float ty = (ay + b1.y) + (b2.y + b3.y);
        fvx = __logf(tx) + M + f0x;
        fvy = __logf(ty) + M + f0y;
        M = rlane(fvx, 0);          // absolute normalizer = fv[tag 0]
        px = __expf(fvx - M);
        py = __expf(fvy - M);
        psel = (w >= 2) ? py : px;

        // rotate feats pipeline
        f0x = f1x; f0y = f1y;
        f1x = f2x; f1y = f2y;
        f2x = f3x; f2y = f3y;
        f3x = fnx; f3y = fny;
    }

    // ---- gold path score (all 256 threads) ----
    const int* tg = targets + b * SS;
    float g = 0.f;
#pragma unroll
    for (int s = t; s < SS; s += 256) {
        int cur  = tg[s];
        int prev = (s == 0) ? START_TAG : tg[s - 1];
        g += trans[cur * TT + prev] + feats[bst + (size_t)s * TT + cur];
    }
    if (t == 0) g += trans[STOP_TAG * TT + tg[SS - 1]];
    g = wave_sum(g);
    if (l == 0) redz[w] = g;

    // ---- alpha = LSE(fv + trans[STOP,:]) on wave 0 ----
    if (w == 0) {
        float vx = fvx + trans[STOP_TAG * TT + l];
        float vy = fvy + trans[STOP_TAG * TT + l + 64];
        float m = wave_max(fmaxf(vx, vy));
        float e = __expf(vx - m) + __expf(vy - m);
        e = wave_sum(e);
        if (l == 0) galpha = m + __logf(e);
    }
    __syncthreads();

    if (t == 0) out[b] = ((redz[0] + redz[1]) + (redz[2] + redz[3])) - galpha;
}

extern "C" void kernel_launch(void* const* d_in, const int* in_sizes, int n_in,
                              void* d_out, int out_size, void* d_ws, size_t ws_size,
                              hipStream_t stream) {
    const float* feats   = (const float*)d_in[0];
    const float* trans   = (const float*)d_in[1];
    const int*   targets = (const int*)d_in[2];
    float*       out     = (float*)d_out;
    crf_fwd_kernel<<<dim3(NB), dim3(256), 0, stream>>>(feats, trans, targets, out);
}

// Round 3
// 317.530 us; speedup vs baseline: 1.5851x; 1.2794x over previous
//
#include <hip/hip_runtime.h>
#include <math.h>

#define TT 128
#define SS 512
#define NB 256
#define START_TAG 126
#define STOP_TAG 127

__device__ __forceinline__ float rlane(float v, int lane) {
    return __int_as_float(__builtin_amdgcn_readlane(__float_as_int(v), lane));
}
__device__ __forceinline__ float wave_max(float v) {
#pragma unroll
    for (int off = 32; off >= 1; off >>= 1) v = fmaxf(v, __shfl_xor(v, off));
    return v;
}
__device__ __forceinline__ float wave_sum(float v) {
#pragma unroll
    for (int off = 32; off >= 1; off >>= 1) v += __shfl_xor(v, off);
    return v;
}

// One block per batch. 4 waves; wave w owns k-quarter [32w, 32w+32).
// Lane l owns tag pair (l, l+64). E2 in TRUE VGPRs (launch_bounds(256,1):
// occupancy is structurally 1 block/CU, so minimizing VGPRs buys nothing --
// cap at 512 so the 64-float E fragment stays out of AGPR/scratch).
// psel = this wave's half of p; dot = 32 readlane + 64 fmac, no LDS.
// One barrier per step (parity double-buffered partials), s-loop unrolled x2.
__global__ __launch_bounds__(256, 1) void crf_fwd_kernel(
    const float* __restrict__ feats,
    const float* __restrict__ trans,
    const int*   __restrict__ targets,
    float*       __restrict__ out)
{
    const int t = threadIdx.x;
    const int b = blockIdx.x;
    const int w = t >> 6;
    const int l = t & 63;

    __shared__ float2 part[2][4][64];   // [parity][wave][lane]
    __shared__ float redz[4];
    __shared__ float galpha;

    // ---- E fragment in VGPRs ----
    float2 E2[32];
    {
        const float* r0 = trans + l * TT + w * 32;
        const float* r1 = trans + (l + 64) * TT + w * 32;
#pragma unroll
        for (int j = 0; j < 32; j += 4) {
            float4 a0 = *reinterpret_cast<const float4*>(r0 + j);
            float4 a1 = *reinterpret_cast<const float4*>(r1 + j);
            E2[j + 0] = make_float2(__expf(a0.x), __expf(a1.x));
            E2[j + 1] = make_float2(__expf(a0.y), __expf(a1.y));
            E2[j + 2] = make_float2(__expf(a0.z), __expf(a1.z));
            E2[j + 3] = make_float2(__expf(a0.w), __expf(a1.w));
        }
    }

    const size_t bst = (size_t)b * (SS * TT);
    const float* fb = feats + bst + l;

    // feats register pipeline, depth 4 (redundant across waves; L1 absorbs)
    float fx0 = fb[0 * TT], fy0 = fb[0 * TT + 64];
    float fx1 = fb[1 * TT], fy1 = fb[1 * TT + 64];
    float fx2 = fb[2 * TT], fy2 = fb[2 * TT + 64];
    float fx3 = fb[3 * TT], fy3 = fb[3 * TT + 64];

    // init: p one-hot at START=126 => psel nonzero only on waves 2/3, lane 62
    float psel = (w >= 2) ? ((l == 62) ? 1.f : 0.f) : 0.f;
    float M = 0.f;
    float fvx = 0.f, fvy = 0.f;
    const int base = (w & 1) << 5;

#define DOT(AX, AY)                                                     \
    {                                                                   \
        AX = 0.f; AY = 0.f;                                             \
        _Pragma("unroll")                                               \
        for (int j = 0; j < 32; ++j) {                                  \
            float pj = rlane(psel, base + j);                           \
            AX = fmaf(pj, E2[j].x, AX);                                 \
            AY = fmaf(pj, E2[j].y, AY);                                 \
        }                                                               \
    }

#define COMBINE(P, AX, AY, FNX, FNY)                                    \
    {                                                                   \
        float2 c1 = part[P][w ^ 1][l];                                  \
        float2 c2 = part[P][w ^ 2][l];                                  \
        float2 c3 = part[P][w ^ 3][l];                                  \
        float tx = (AX + c1.x) + (c2.x + c3.x);                         \
        float ty = (AY + c1.y) + (c2.y + c3.y);                         \
        fvx = __logf(tx) + M + fx0;                                     \
        fvy = __logf(ty) + M + fy0;                                     \
        M = rlane(fvx, 0);                                              \
        psel = __expf(((w >= 2) ? fvy : fvx) - M);                      \
        fx0 = fx1; fy0 = fy1; fx1 = fx2; fy1 = fy2;                     \
        fx2 = fx3; fy2 = fy3; fx3 = FNX; fy3 = FNY;                     \
    }

    for (int s = 0; s < SS; s += 2) {
        // ---- sub-step A (parity 0) ----
        int sn = s + 4; sn = (sn < SS) ? sn : (SS - 1);
        float fnx = fb[(size_t)sn * TT];
        float fny = fb[(size_t)sn * TT + 64];
        float ax, ay;
        DOT(ax, ay);
        part[0][w][l] = make_float2(ax, ay);
        __syncthreads();
        COMBINE(0, ax, ay, fnx, fny);

        // ---- sub-step B (parity 1) ----
        sn = s + 5; sn = (sn < SS) ? sn : (SS - 1);
        fnx = fb[(size_t)sn * TT];
        fny = fb[(size_t)sn * TT + 64];
        DOT(ax, ay);
        part[1][w][l] = make_float2(ax, ay);
        __syncthreads();
        COMBINE(1, ax, ay, fnx, fny);
    }
#undef DOT
#undef COMBINE

    // ---- gold path score (all 256 threads) ----
    const int* tg = targets + b * SS;
    float g = 0.f;
#pragma unroll
    for (int s = t; s < SS; s += 256) {
        int cur  = tg[s];
        int prev = (s == 0) ? START_TAG : tg[s - 1];
        g += trans[cur * TT + prev] + feats[bst + (size_t)s * TT + cur];
    }
    if (t == 0) g += trans[STOP_TAG * TT + tg[SS - 1]];
    g = wave_sum(g);
    if (l == 0) redz[w] = g;

    // ---- alpha = LSE(fv + trans[STOP,:]) on wave 0 ----
    if (w == 0) {
        float vx = fvx + trans[STOP_TAG * TT + l];
        float vy = fvy + trans[STOP_TAG * TT + l + 64];
        float m = wave_max(fmaxf(vx, vy));
        float e = __expf(vx - m) + __expf(vy - m);
        e = wave_sum(e);
        if (l == 0) galpha = m + __logf(e);
    }
    __syncthreads();

    if (t == 0) out[b] = ((redz[0] + redz[1]) + (redz[2] + redz[3])) - galpha;
}

extern "C" void kernel_launch(void* const* d_in, const int* in_sizes, int n_in,
                              void* d_out, int out_size, void* d_ws, size_t ws_size,
                              hipStream_t stream) {
    const float* feats   = (const float*)d_in[0];
    const float* trans   = (const float*)d_in[1];
    const int*   targets = (const int*)d_in[2];
    float*       out     = (float*)d_out;
    crf_fwd_kernel<<<dim3(NB), dim3(256), 0, stream>>>(feats, trans, targets, out);
}